// Round 8
// baseline (94.841 us; speedup 1.0000x reference)
//
#include <hip/hip_runtime.h>

#define NS 4096
#define NTOK 65536            // 16 * 4096 tokens
#define TOKB 64               // output tokens per block
#define GRID 1024             // NTOK / TOKB
#define NLOC 80               // TOKB + 2*8 halo tokens staged
#define NTILE 5               // NLOC / 16 token-tiles
#define WTS_V 278528u         // (16*4096*17)/4 float4 of weights
#define F4MAX 1048575         // NTOK*16 - 1 (flat float4 index clamp)

typedef __attribute__((ext_vector_type(8))) short bfrag;   // 8 bf16 = 4 VGPR
typedef __attribute__((ext_vector_type(4))) float f32x4;

__device__ __forceinline__ unsigned short f2bf(float f) {
    union { unsigned int i; float f; } c; c.f = f;
    unsigned int u = c.i;
    unsigned int r = u + 0x7FFFu + ((u >> 16) & 1u);   // RNE
    return (unsigned short)(r >> 16);
}

// out[b,s,:] = (sum_{u=s-8..s+8 in-batch} relu((x+pe)[b,u]@W1 + b1)) @ (Wv@W2) + b2
// weights = all ones (softmax over singleton axis; Wq/Wk dead).
// h-GEMM in bf16 MFMA (fp32 accum); everything else fp32.
__global__ __launch_bounds__(256, 4) void fused(
    const float* __restrict__ x, const float* __restrict__ pe,
    const float* __restrict__ w1p, const float* __restrict__ b1p,
    const float* __restrict__ wvp, const float* __restrict__ w2p,
    const float* __restrict__ b2p,
    float* __restrict__ out, float* __restrict__ wts)
{
    __shared__ bfrag Xb[NLOC * 8];  // (x+pe) bf16, 80 tokens x 64, chunk-swizzled
    __shared__ bfrag Wf[512];       // W1 bf16 B-fragments [kh][dtile][lane]
    __shared__ float B1s[64], M0s[64], M1s[64], W2S[128];
    __shared__ float PL[82][2];     // p per local token (80 used)

    const int tid  = threadIdx.x;
    const int blk  = blockIdx.x;
    const int lane = tid & 63;
    const int wid  = tid >> 6;

    // ---- stage Xb: tokens g0-8 .. g0+71 as bf16, 16B chunks XOR-swizzled ----
    const int gbase4 = blk * 1024 - 128;           // float4 idx of token g0-8
    const float4* x4 = (const float4*)x;
    const float4* p4 = (const float4*)pe;
    #pragma unroll
    for (int it = 0; it < 3; ++it) {
        int cidx = it * 256 + tid;                 // chunk = 8 bf16 of one token
        if (cidx < NLOC * 8) {
            int f0 = gbase4 + cidx * 2, f1 = f0 + 1;
            f0 = f0 < 0 ? 0 : (f0 > F4MAX ? F4MAX : f0);
            f1 = f1 < 0 ? 0 : (f1 > F4MAX ? F4MAX : f1);
            float4 a = x4[f0], b = x4[f1], c = p4[f0], d = p4[f1];
            union { unsigned short u[8]; bfrag v; } P;
            P.u[0] = f2bf(a.x + c.x); P.u[1] = f2bf(a.y + c.y);
            P.u[2] = f2bf(a.z + c.z); P.u[3] = f2bf(a.w + c.w);
            P.u[4] = f2bf(b.x + d.x); P.u[5] = f2bf(b.y + d.y);
            P.u[6] = f2bf(b.z + d.z); P.u[7] = f2bf(b.w + d.w);
            int tl = cidx >> 3;
            int sc = (cidx & 7) ^ (tl & 7);        // bank-spread chunks
            Xb[tl * 8 + sc] = P.v;
        }
    }
    // ---- stage Wf: B-operand fragments of W1 (k=(l>>4)*8+j+32kh, col=l&15) ----
    #pragma unroll
    for (int s = 0; s < 2; ++s) {
        int slot = s * 256 + tid;                  // 0..511
        int kh = slot >> 8, rem = slot & 255, dt = rem >> 6, l = rem & 63;
        int dd = dt * 16 + (l & 15);
        int kb = kh * 32 + ((l >> 4) << 3);
        union { unsigned short u[8]; bfrag v; } P;
        #pragma unroll
        for (int j = 0; j < 8; ++j) P.u[j] = f2bf(w1p[(kb + j) * 64 + dd]);
        Wf[slot] = P.v;
    }
    if (tid < 64) B1s[tid] = b1p[tid];
    if (tid >= 64 && tid < 192) W2S[tid - 64] = w2p[tid - 64];
    __syncthreads();

    // ---- M = Wv @ W2 (fp32), 128 threads ----
    if (tid < 128) {
        const int o = tid & 1, dd = tid >> 1;
        const float4* wv4 = (const float4*)(wvp + (size_t)dd * 64);
        float m0 = 0.f, m1 = 0.f, m2 = 0.f, m3 = 0.f;
        #pragma unroll
        for (int j4 = 0; j4 < 16; j4 += 4) {
            float4 a = wv4[j4 + 0], b = wv4[j4 + 1], c = wv4[j4 + 2], e = wv4[j4 + 3];
            int jb = j4 * 4;
            m0 = fmaf(a.x, W2S[(jb+ 0)*2+o], m0); m0 = fmaf(a.y, W2S[(jb+ 1)*2+o], m0);
            m0 = fmaf(a.z, W2S[(jb+ 2)*2+o], m0); m0 = fmaf(a.w, W2S[(jb+ 3)*2+o], m0);
            m1 = fmaf(b.x, W2S[(jb+ 4)*2+o], m1); m1 = fmaf(b.y, W2S[(jb+ 5)*2+o], m1);
            m1 = fmaf(b.z, W2S[(jb+ 6)*2+o], m1); m1 = fmaf(b.w, W2S[(jb+ 7)*2+o], m1);
            m2 = fmaf(c.x, W2S[(jb+ 8)*2+o], m2); m2 = fmaf(c.y, W2S[(jb+ 9)*2+o], m2);
            m2 = fmaf(c.z, W2S[(jb+10)*2+o], m2); m2 = fmaf(c.w, W2S[(jb+11)*2+o], m2);
            m3 = fmaf(e.x, W2S[(jb+12)*2+o], m3); m3 = fmaf(e.y, W2S[(jb+13)*2+o], m3);
            m3 = fmaf(e.z, W2S[(jb+14)*2+o], m3); m3 = fmaf(e.w, W2S[(jb+15)*2+o], m3);
        }
        float v = (m0 + m1) + (m2 + m3);
        if (o) M1s[dd] = v; else M0s[dd] = v;
    }
    __syncthreads();

    // ---- MFMA: wave handles token-tile tau = wid (wave 0 also tau = 4) ----
    const int cl = lane & 15;                      // col within d-tile
    float biasv[4], m0v[4], m1v[4];
    #pragma unroll
    for (int dt = 0; dt < 4; ++dt) {
        biasv[dt] = B1s[dt * 16 + cl];
        m0v[dt]   = M0s[dt * 16 + cl];
        m1v[dt]   = M1s[dt * 16 + cl];
    }
    const int sbase = (blk & 63) * TOKB - 8;       // in-batch index of local tok 0
    for (int tau = wid; tau < NTILE; tau += 4) {
        float pr0[4] = {0.f,0.f,0.f,0.f}, pr1[4] = {0.f,0.f,0.f,0.f};
        const int arow = (tau * 16 + cl) * 8;
        #pragma unroll
        for (int dt = 0; dt < 4; ++dt) {
            f32x4 acc = {0.f, 0.f, 0.f, 0.f};
            #pragma unroll
            for (int kh = 0; kh < 2; ++kh) {
                bfrag av = Xb[arow + (((kh << 2) + (lane >> 4)) ^ (lane & 7))];
                bfrag bv = Wf[(kh * 4 + dt) * 64 + lane];
                acc = __builtin_amdgcn_mfma_f32_16x16x32_bf16(av, bv, acc, 0, 0, 0);
            }
            #pragma unroll
            for (int rg = 0; rg < 4; ++rg) {       // D: col=lane&15, row=(lane>>4)*4+rg
                float h = fmaxf(acc[rg] + biasv[dt], 0.f);
                pr0[rg] = fmaf(h, m0v[dt], pr0[rg]);
                pr1[rg] = fmaf(h, m1v[dt], pr1[rg]);
            }
        }
        #pragma unroll
        for (int rg = 0; rg < 4; ++rg) {           // reduce over 16 col-lanes
            #pragma unroll
            for (int m = 1; m < 16; m <<= 1) {
                pr0[rg] += __shfl_xor(pr0[rg], m);
                pr1[rg] += __shfl_xor(pr1[rg], m);
            }
        }
        if ((lane & 15) == 0) {
            const int rgrp = lane >> 4;
            #pragma unroll
            for (int rg = 0; rg < 4; ++rg) {
                int tl = tau * 16 + rgrp * 4 + rg;
                bool valid = (unsigned)(sbase + tl) < (unsigned)NS;  // batch mask
                PL[tl][0] = valid ? pr0[rg] : 0.f;
                PL[tl][1] = valid ? pr1[rg] : 0.f;
            }
        }
    }
    __syncthreads();

    // ---- window sum (+/-8) + b2, write out ----
    if (tid < TOKB) {
        float ax = b2p[0], ay = b2p[1];
        #pragma unroll
        for (int k = 0; k <= 16; ++k) {
            float2 v = *(const float2*)&PL[tid + k][0];
            ax += v.x; ay += v.y;
        }
        ((float2*)out)[(size_t)blk * TOKB + tid] = make_float2(ax, ay);
    }

    // ---- weights = 1.0 ----
    {
        float4* wp = (float4*)wts;
        const float4 one4 = make_float4(1.f, 1.f, 1.f, 1.f);
        for (unsigned idx = (unsigned)blk * 256u + (unsigned)tid;
             idx < WTS_V; idx += (unsigned)GRID * 256u)
            wp[idx] = one4;
    }
}

extern "C" void kernel_launch(void* const* d_in, const int* in_sizes, int n_in,
                              void* d_out, int out_size, void* d_ws, size_t ws_size,
                              hipStream_t stream) {
    const float* x  = (const float*)d_in[0];
    const float* pe = (const float*)d_in[1];
    const float* w1 = (const float*)d_in[2];
    const float* b1 = (const float*)d_in[3];
    // d_in[4]=Wq, d_in[5]=Wk: dead (softmax over singleton axis => weights==1)
    const float* wv = (const float*)d_in[6];
    const float* w2 = (const float*)d_in[7];
    const float* b2 = (const float*)d_in[8];

    float* out = (float*)d_out;                 // (B,S,2) = 131072 floats
    float* wts = out + (size_t)NTOK * 2;        // (B,S,1,17) = 1114112 floats

    fused<<<GRID, 256, 0, stream>>>(x, pe, w1, b1, wv, w2, b2, out, wts);
}

// Round 9
// 93.640 us; speedup vs baseline: 1.0128x; 1.0128x over previous
//
#include <hip/hip_runtime.h>
#include <hip/hip_bf16.h>

#define NS 4096
#define NTOK 65536            // 16 * 4096 tokens
#define TOKB 128              // output tokens per block
#define GRID 512              // NTOK / TOKB
#define NLOC 144              // TOKB + 2*8 halo tokens staged
#define NTILE 9               // NLOC / 16 token-tiles
#define WTS_V 278528u         // (16*4096*17)/4 float4 of weights
#define F4MAX 1048575         // NTOK*16 - 1 (flat float4 index clamp)

typedef __attribute__((ext_vector_type(8))) short bfrag;   // 8 bf16 = 4 VGPR
typedef __attribute__((ext_vector_type(4))) float f32x4;

// out[b,s,:] = (sum_{u=s-8..s+8 in-batch} relu((x+pe)[b,u]@W1 + b1)) @ (Wv@W2) + b2
// weights = all ones (softmax over singleton axis; Wq/Wk dead).
// h-GEMM in bf16 MFMA (fp32 accum); everything else fp32.
__global__ __launch_bounds__(256, 2) void fused(
    const float* __restrict__ x, const float* __restrict__ pe,
    const float* __restrict__ w1p, const float* __restrict__ b1p,
    const float* __restrict__ wvp, const float* __restrict__ w2p,
    const float* __restrict__ b2p,
    float* __restrict__ out, float* __restrict__ wts)
{
    __shared__ bfrag Xb[NLOC * 8];  // (x+pe) bf16, 144 tokens x 64, chunk-swizzled
    __shared__ bfrag Wf[512];       // W1 bf16 B-fragments [kh][dtile][lane]
    __shared__ float B1s[64], M0s[64], M1s[64];
    __shared__ float PL[146][2];    // p per local token (144 used)

    const int tid  = threadIdx.x;
    const int blk  = blockIdx.x;
    const int lane = tid & 63;
    const int wid  = tid >> 6;

    // ---- stage Xb: tokens g0-8 .. g0+135 as bf16 (cvt_pk), chunk-swizzled ----
    const int gbase4 = blk * 2048 - 128;           // float4 idx of token g0-8
    const float4* x4 = (const float4*)x;
    const float4* p4 = (const float4*)pe;
    #pragma unroll
    for (int it = 0; it < 5; ++it) {
        int cidx = it * 256 + tid;                 // chunk = 8 bf16 of one token
        if (cidx < NLOC * 8) {
            int f0 = gbase4 + cidx * 2, f1 = f0 + 1;
            f0 = f0 < 0 ? 0 : (f0 > F4MAX ? F4MAX : f0);
            f1 = f1 < 0 ? 0 : (f1 > F4MAX ? F4MAX : f1);
            float4 a = x4[f0], b = x4[f1], c = p4[f0], d = p4[f1];
            union { __hip_bfloat162 h[4]; bfrag v; } P;
            P.h[0] = __float22bfloat162_rn(make_float2(a.x + c.x, a.y + c.y));
            P.h[1] = __float22bfloat162_rn(make_float2(a.z + c.z, a.w + c.w));
            P.h[2] = __float22bfloat162_rn(make_float2(b.x + d.x, b.y + d.y));
            P.h[3] = __float22bfloat162_rn(make_float2(b.z + d.z, b.w + d.w));
            int tl = cidx >> 3;
            int sc = (cidx & 7) ^ (tl & 7);        // bank-spread chunks
            Xb[tl * 8 + sc] = P.v;
        }
    }

    // ---- stage Wf: B-operand fragments of W1 (k=(l>>4)*8+j+32kh, col=l&15) ----
    #pragma unroll
    for (int s = 0; s < 2; ++s) {
        int slot = s * 256 + tid;                  // 0..511
        int kh = slot >> 8, rem = slot & 255, dt = rem >> 6, l = rem & 63;
        int dd = dt * 16 + (l & 15);
        int kb = kh * 32 + ((l >> 4) << 3);
        union { __hip_bfloat162 h[4]; bfrag v; } P;
        #pragma unroll
        for (int j = 0; j < 4; ++j) {
            float lo = w1p[(kb + 2*j)     * 64 + dd];
            float hi = w1p[(kb + 2*j + 1) * 64 + dd];
            P.h[j] = __float22bfloat162_rn(make_float2(lo, hi));
        }
        Wf[slot] = P.v;
    }
    if (tid >= 192) B1s[tid - 192] = b1p[tid - 192];

    // ---- M = Wv @ W2 (fp32), pre-barrier; W2 via uniform L1-broadcast loads ----
    if (tid < 128) {
        const int o = tid & 1, dd = tid >> 1;
        const float4* wv4 = (const float4*)(wvp + (size_t)dd * 64);
        const float2* w22 = (const float2*)w2p;    // w22[j] = (W2[j][0], W2[j][1])
        float m0 = 0.f, m1 = 0.f, m2 = 0.f, m3 = 0.f;
        #pragma unroll
        for (int q = 0; q < 16; q += 4) {
            float4 a = wv4[q], b = wv4[q+1], c = wv4[q+2], e = wv4[q+3];
            #pragma unroll
            for (int r = 0; r < 4; ++r) {
                float2 u = w22[4*q + r];      float wa = o ? u.y : u.x;
                float2 v = w22[4*q + 4 + r];  float wb = o ? v.y : v.x;
                float2 w = w22[4*q + 8 + r];  float wc = o ? w.y : w.x;
                float2 z = w22[4*q + 12 + r]; float we = o ? z.y : z.x;
                float av = r == 0 ? a.x : r == 1 ? a.y : r == 2 ? a.z : a.w;
                float bv = r == 0 ? b.x : r == 1 ? b.y : r == 2 ? b.z : b.w;
                float cv = r == 0 ? c.x : r == 1 ? c.y : r == 2 ? c.z : c.w;
                float ev = r == 0 ? e.x : r == 1 ? e.y : r == 2 ? e.z : e.w;
                m0 = fmaf(av, wa, m0);
                m1 = fmaf(bv, wb, m1);
                m2 = fmaf(cv, wc, m2);
                m3 = fmaf(ev, we, m3);
            }
        }
        float v = (m0 + m1) + (m2 + m3);
        if (o) M1s[dd] = v; else M0s[dd] = v;
    }
    __syncthreads();

    // ---- MFMA: wave handles token-tiles tau = wid, wid+4, wid+8 ----
    const int cl = lane & 15;                      // col within d-tile
    float biasv[4], m0v[4], m1v[4];
    #pragma unroll
    for (int dt = 0; dt < 4; ++dt) {
        biasv[dt] = B1s[dt * 16 + cl];
        m0v[dt]   = M0s[dt * 16 + cl];
        m1v[dt]   = M1s[dt * 16 + cl];
    }
    const int sbase = (blk & 31) * TOKB - 8;       // in-batch index of local tok 0
    for (int tau = wid; tau < NTILE; tau += 4) {
        float pr0[4] = {0.f,0.f,0.f,0.f}, pr1[4] = {0.f,0.f,0.f,0.f};
        const int arow = (tau * 16 + cl) * 8;
        #pragma unroll
        for (int dt = 0; dt < 4; ++dt) {
            f32x4 acc = {0.f, 0.f, 0.f, 0.f};
            #pragma unroll
            for (int kh = 0; kh < 2; ++kh) {
                bfrag av = Xb[arow + (((kh << 2) + (lane >> 4)) ^ (lane & 7))];
                bfrag bv = Wf[(kh * 4 + dt) * 64 + lane];
                acc = __builtin_amdgcn_mfma_f32_16x16x32_bf16(av, bv, acc, 0, 0, 0);
            }
            #pragma unroll
            for (int rg = 0; rg < 4; ++rg) {       // D: col=lane&15, row=(lane>>4)*4+rg
                float h = fmaxf(acc[rg] + biasv[dt], 0.f);
                pr0[rg] = fmaf(h, m0v[dt], pr0[rg]);
                pr1[rg] = fmaf(h, m1v[dt], pr1[rg]);
            }
        }
        #pragma unroll
        for (int rg = 0; rg < 4; ++rg) {           // reduce over 16 col-lanes
            #pragma unroll
            for (int m = 1; m < 16; m <<= 1) {
                pr0[rg] += __shfl_xor(pr0[rg], m);
                pr1[rg] += __shfl_xor(pr1[rg], m);
            }
        }
        if ((lane & 15) == 0) {
            const int rgrp = lane >> 4;
            #pragma unroll
            for (int rg = 0; rg < 4; ++rg) {
                int tl = tau * 16 + rgrp * 4 + rg;
                bool valid = (unsigned)(sbase + tl) < (unsigned)NS;  // batch mask
                PL[tl][0] = valid ? pr0[rg] : 0.f;
                PL[tl][1] = valid ? pr1[rg] : 0.f;
            }
        }
    }

    // ---- weights = 1.0 (issue stores before barrier; drain under it) ----
    {
        float4* wp = (float4*)wts;
        const float4 one4 = make_float4(1.f, 1.f, 1.f, 1.f);
        for (unsigned idx = (unsigned)blk * 256u + (unsigned)tid;
             idx < WTS_V; idx += (unsigned)GRID * 256u)
            wp[idx] = one4;
    }
    __syncthreads();

    // ---- window sum (+/-8) + b2, write out ----
    if (tid < TOKB) {
        float ax = b2p[0], ay = b2p[1];
        #pragma unroll
        for (int k = 0; k <= 16; ++k) {
            float2 v = *(const float2*)&PL[tid + k][0];
            ax += v.x; ay += v.y;
        }
        ((float2*)out)[(size_t)blk * TOKB + tid] = make_float2(ax, ay);
    }
}

extern "C" void kernel_launch(void* const* d_in, const int* in_sizes, int n_in,
                              void* d_out, int out_size, void* d_ws, size_t ws_size,
                              hipStream_t stream) {
    const float* x  = (const float*)d_in[0];
    const float* pe = (const float*)d_in[1];
    const float* w1 = (const float*)d_in[2];
    const float* b1 = (const float*)d_in[3];
    // d_in[4]=Wq, d_in[5]=Wk: dead (softmax over singleton axis => weights==1)
    const float* wv = (const float*)d_in[6];
    const float* w2 = (const float*)d_in[7];
    const float* b2 = (const float*)d_in[8];

    float* out = (float*)d_out;                 // (B,S,2) = 131072 floats
    float* wts = out + (size_t)NTOK * 2;        // (B,S,1,17) = 1114112 floats

    fused<<<GRID, 256, 0, stream>>>(x, pe, w1, b1, wv, w2, b2, out, wts);
}

// Round 10
// 93.184 us; speedup vs baseline: 1.0178x; 1.0049x over previous
//
#include <hip/hip_runtime.h>
#include <hip/hip_bf16.h>

#define NS 4096
#define NTOK 65536            // 16 * 4096 tokens
#define TOKB 128              // output tokens per block
#define GRID 512              // NTOK / TOKB
#define NTILE 9               // (TOKB + 16 halo) / 16 token-tiles
#define WTS_V 278528u         // (16*4096*17)/4 float4 of weights

typedef __attribute__((ext_vector_type(8))) short bfrag;   // 8 bf16 = 4 VGPR
typedef __attribute__((ext_vector_type(4))) float f32x4;

// Load the A-operand inputs for one 16-token tile directly into registers.
// Lane l covers token tau*16 + (l&15), k-slice (l>>4)*8 (+32 for kh=1).
#define ISSUE_TILE(XB, PB, TAU)                                         \
    {                                                                   \
        int g_ = blk * TOKB - 8 + (TAU) * 16 + cl;                      \
        g_ = g_ < 0 ? 0 : (g_ > NTOK - 1 ? NTOK - 1 : g_);              \
        const float4* xa_ = x4 + (size_t)g_ * 16 + kq * 2;              \
        const float4* pa_ = p4 + (size_t)g_ * 16 + kq * 2;              \
        XB[0] = xa_[0]; XB[1] = xa_[1];   /* kh=0 */                    \
        XB[2] = xa_[8]; XB[3] = xa_[9];   /* kh=1 */                    \
        PB[0] = pa_[0]; PB[1] = pa_[1];                                 \
        PB[2] = pa_[8]; PB[3] = pa_[9];                                 \
    }

__device__ __forceinline__ void compute_tile(
    const float4 (&xb)[4], const float4 (&pb)[4], int tau,
    const bfrag (&Wf)[512], const float* biasv, const float* m0v,
    const float* m1v, int lane, int sbase, float (&PL)[146][2])
{
    union { __hip_bfloat162 h[4]; bfrag v; } A0, A1;
    A0.h[0] = __float22bfloat162_rn(make_float2(xb[0].x + pb[0].x, xb[0].y + pb[0].y));
    A0.h[1] = __float22bfloat162_rn(make_float2(xb[0].z + pb[0].z, xb[0].w + pb[0].w));
    A0.h[2] = __float22bfloat162_rn(make_float2(xb[1].x + pb[1].x, xb[1].y + pb[1].y));
    A0.h[3] = __float22bfloat162_rn(make_float2(xb[1].z + pb[1].z, xb[1].w + pb[1].w));
    A1.h[0] = __float22bfloat162_rn(make_float2(xb[2].x + pb[2].x, xb[2].y + pb[2].y));
    A1.h[1] = __float22bfloat162_rn(make_float2(xb[2].z + pb[2].z, xb[2].w + pb[2].w));
    A1.h[2] = __float22bfloat162_rn(make_float2(xb[3].x + pb[3].x, xb[3].y + pb[3].y));
    A1.h[3] = __float22bfloat162_rn(make_float2(xb[3].z + pb[3].z, xb[3].w + pb[3].w));

    float pr0[4] = {0.f,0.f,0.f,0.f}, pr1[4] = {0.f,0.f,0.f,0.f};
    #pragma unroll
    for (int dt = 0; dt < 4; ++dt) {
        f32x4 acc = {0.f, 0.f, 0.f, 0.f};
        acc = __builtin_amdgcn_mfma_f32_16x16x32_bf16(A0.v, Wf[dt * 64 + lane], acc, 0, 0, 0);
        acc = __builtin_amdgcn_mfma_f32_16x16x32_bf16(A1.v, Wf[(4 + dt) * 64 + lane], acc, 0, 0, 0);
        #pragma unroll
        for (int rg = 0; rg < 4; ++rg) {       // D: col=lane&15, row=(lane>>4)*4+rg
            float h = fmaxf(acc[rg] + biasv[dt], 0.f);
            pr0[rg] = fmaf(h, m0v[dt], pr0[rg]);
            pr1[rg] = fmaf(h, m1v[dt], pr1[rg]);
        }
    }
    #pragma unroll
    for (int rg = 0; rg < 4; ++rg) {           // reduce over the 16 col-lanes
        #pragma unroll
        for (int m = 1; m < 16; m <<= 1) {
            pr0[rg] += __shfl_xor(pr0[rg], m);
            pr1[rg] += __shfl_xor(pr1[rg], m);
        }
    }
    if ((lane & 15) == 0) {
        const int rgrp = lane >> 4;
        #pragma unroll
        for (int rg = 0; rg < 4; ++rg) {
            int tl = tau * 16 + rgrp * 4 + rg;
            bool valid = (unsigned)(sbase + tl) < (unsigned)NS;  // batch mask
            PL[tl][0] = valid ? pr0[rg] : 0.f;
            PL[tl][1] = valid ? pr1[rg] : 0.f;
        }
    }
}

// out[b,s,:] = (sum_{u=s-8..s+8 in-batch} relu((x+pe)[b,u]@W1 + b1)) @ (Wv@W2) + b2
// weights = all ones (softmax over singleton axis; Wq/Wk dead).
// A-fragments built in registers from global (no X LDS round-trip).
__global__ __launch_bounds__(256, 2) void fused(
    const float* __restrict__ x, const float* __restrict__ pe,
    const float* __restrict__ w1p, const float* __restrict__ b1p,
    const float* __restrict__ wvp, const float* __restrict__ w2p,
    const float* __restrict__ b2p,
    float* __restrict__ out, float* __restrict__ wts)
{
    __shared__ bfrag Wf[512];       // W1 bf16 B-fragments [kh][dtile][lane]
    __shared__ float B1s[64], M0s[64], M1s[64];
    __shared__ float PL[146][2];    // p per local token (144 used)

    const int tid  = threadIdx.x;
    const int blk  = blockIdx.x;
    const int lane = tid & 63;
    const int wid  = tid >> 6;
    const int cl   = lane & 15;     // token-within-tile / output col
    const int kq   = lane >> 4;     // k-quarter

    const float4* x4 = (const float4*)x;
    const float4* p4 = (const float4*)pe;

    const int t0 = wid, t1 = wid + 4, t2 = wid + 8;   // t2 only valid for wid==0

    // ---- issue A loads for my first two tiles (independent of LDS) ----
    float4 xb0[4], pb0[4], xb1[4], pb1[4];
    ISSUE_TILE(xb0, pb0, t0);
    ISSUE_TILE(xb1, pb1, t1);

    // ---- stage Wf: B-operand fragments of W1 (k=(l>>4)*8+j+32kh, col=l&15) ----
    #pragma unroll
    for (int s = 0; s < 2; ++s) {
        int slot = s * 256 + tid;                  // 0..511
        int kh = slot >> 8, rem = slot & 255, dt = rem >> 6, l = rem & 63;
        int dd = dt * 16 + (l & 15);
        int kb = kh * 32 + ((l >> 4) << 3);
        union { __hip_bfloat162 h[4]; bfrag v; } P;
        #pragma unroll
        for (int j = 0; j < 4; ++j) {
            float lo = w1p[(kb + 2*j)     * 64 + dd];
            float hi = w1p[(kb + 2*j + 1) * 64 + dd];
            P.h[j] = __float22bfloat162_rn(make_float2(lo, hi));
        }
        Wf[slot] = P.v;
    }
    if (tid >= 192) B1s[tid - 192] = b1p[tid - 192];

    // ---- M = Wv @ W2 (fp32), pre-barrier; W2 via uniform loads ----
    if (tid < 128) {
        const int o = tid & 1, dd = tid >> 1;
        const float4* wv4 = (const float4*)(wvp + (size_t)dd * 64);
        const float2* w22 = (const float2*)w2p;
        float m0 = 0.f, m1 = 0.f, m2 = 0.f, m3 = 0.f;
        #pragma unroll
        for (int q = 0; q < 16; q += 4) {
            float4 a = wv4[q], b = wv4[q+1], c = wv4[q+2], e = wv4[q+3];
            #pragma unroll
            for (int r = 0; r < 4; ++r) {
                float2 u = w22[4*q + r];      float wa = o ? u.y : u.x;
                float2 v = w22[4*q + 4 + r];  float wb = o ? v.y : v.x;
                float2 w = w22[4*q + 8 + r];  float wc = o ? w.y : w.x;
                float2 z = w22[4*q + 12 + r]; float we = o ? z.y : z.x;
                float av = r == 0 ? a.x : r == 1 ? a.y : r == 2 ? a.z : a.w;
                float bv = r == 0 ? b.x : r == 1 ? b.y : r == 2 ? b.z : b.w;
                float cv = r == 0 ? c.x : r == 1 ? c.y : r == 2 ? c.z : c.w;
                float ev = r == 0 ? e.x : r == 1 ? e.y : r == 2 ? e.z : e.w;
                m0 = fmaf(av, wa, m0);
                m1 = fmaf(bv, wb, m1);
                m2 = fmaf(cv, wc, m2);
                m3 = fmaf(ev, we, m3);
            }
        }
        float v = (m0 + m1) + (m2 + m3);
        if (o) M1s[dd] = v; else M0s[dd] = v;
    }
    __syncthreads();

    // ---- per-thread bias / projection coefficients ----
    float biasv[4], m0v[4], m1v[4];
    #pragma unroll
    for (int dt = 0; dt < 4; ++dt) {
        biasv[dt] = B1s[dt * 16 + cl];
        m0v[dt]   = M0s[dt * 16 + cl];
        m1v[dt]   = M1s[dt * 16 + cl];
    }
    const int sbase = (blk & 31) * TOKB - 8;       // in-batch index of local tok 0

    // ---- pipelined tile compute (wave 0 owns the 9th tile) ----
    compute_tile(xb0, pb0, t0, Wf, biasv, m0v, m1v, lane, sbase, PL);
    if (t2 < NTILE) ISSUE_TILE(xb0, pb0, t2);      // reuse slot 0 (wid==0 only)
    compute_tile(xb1, pb1, t1, Wf, biasv, m0v, m1v, lane, sbase, PL);
    if (t2 < NTILE)
        compute_tile(xb0, pb0, t2, Wf, biasv, m0v, m1v, lane, sbase, PL);

    // ---- weights = 1.0 (issue stores before barrier; drain under it) ----
    {
        float4* wp = (float4*)wts;
        const float4 one4 = make_float4(1.f, 1.f, 1.f, 1.f);
        for (unsigned idx = (unsigned)blk * 256u + (unsigned)tid;
             idx < WTS_V; idx += (unsigned)GRID * 256u)
            wp[idx] = one4;
    }
    __syncthreads();

    // ---- window sum (+/-8) + b2, write out ----
    if (tid < TOKB) {
        float ax = b2p[0], ay = b2p[1];
        #pragma unroll
        for (int k = 0; k <= 16; ++k) {
            float2 v = *(const float2*)&PL[tid + k][0];
            ax += v.x; ay += v.y;
        }
        ((float2*)out)[(size_t)blk * TOKB + tid] = make_float2(ax, ay);
    }
}

extern "C" void kernel_launch(void* const* d_in, const int* in_sizes, int n_in,
                              void* d_out, int out_size, void* d_ws, size_t ws_size,
                              hipStream_t stream) {
    const float* x  = (const float*)d_in[0];
    const float* pe = (const float*)d_in[1];
    const float* w1 = (const float*)d_in[2];
    const float* b1 = (const float*)d_in[3];
    // d_in[4]=Wq, d_in[5]=Wk: dead (softmax over singleton axis => weights==1)
    const float* wv = (const float*)d_in[6];
    const float* w2 = (const float*)d_in[7];
    const float* b2 = (const float*)d_in[8];

    float* out = (float*)d_out;                 // (B,S,2) = 131072 floats
    float* wts = out + (size_t)NTOK * 2;        // (B,S,1,17) = 1114112 floats

    fused<<<GRID, 256, 0, stream>>>(x, pe, w1, b1, wv, w2, b2, out, wts);
}